// Round 6
// baseline (204.108 us; speedup 1.0000x reference)
//
#include <hip/hip_runtime.h>
#include <math.h>

namespace {

constexpr int kB    = 16384;
constexpr int kS0   = 7;
constexpr int kS1   = 7;
constexpr int kD    = 30;
constexpr int kCells = kB * kS0 * kS1;   // 802816
constexpr int TPB   = 256;
constexpr int NBLK  = kCells / TPB;      // 3136 (exact)
constexpr int NSLOT = 64;                // spread-atomic partial slots
constexpr float kInv7 = 1.0f / 7.0f;
constexpr float kWC = 5.0f;
constexpr float kWN = 0.5f;

// 16B load with 8B alignment guarantee (cell stride is 120B = 8-aligned).
// gfx950 global VMEM supports dword-aligned dwordx4, so this still emits a
// single global_load_dwordx4.
struct __attribute__((packed, aligned(8))) F4 { float a, b, c, d; };
struct __attribute__((packed, aligned(8))) F2 { float a, b; };

__device__ __forceinline__ float sigm(float x) {
    return 1.0f / (1.0f + __expf(-x));
}

__global__ void __launch_bounds__(TPB) yolo_loss_kernel(
    const float* __restrict__ pred,
    const int*   __restrict__ grid,
    const float* __restrict__ tbox,
    const int*   __restrict__ tcls,
    float* __restrict__ partials)   // 64 f32 slots in d_ws, pre-zeroed
{
    const int tid  = threadIdx.x;
    const int cell = blockIdx.x * TPB + tid;
    const int wave = tid >> 6;

    // --- direct per-thread loads, straight into compute registers.
    // No LDS, no barrier, no vmcnt(0)-drain: the compiler pipelines these
    // with fine-grained vmcnt(N). A wave's footprint is one contiguous
    // 7.68KB region -> every line fetched once (L1/MSHR merge).
    const char* __restrict__ pbase =
        reinterpret_cast<const char*>(pred) + (size_t)cell * (kD * 4);

    float f[kD];
    #pragma unroll
    for (int k = 0; k < 7; ++k) {
        const F4 v = *reinterpret_cast<const F4*>(pbase + 16 * k);
        f[4 * k + 0] = v.a; f[4 * k + 1] = v.b;
        f[4 * k + 2] = v.c; f[4 * k + 3] = v.d;
    }
    {
        const F2 v = *reinterpret_cast<const F2*>(pbase + 112);
        f[28] = v.a; f[29] = v.b;
    }

    const float4 tb4 = reinterpret_cast<const float4*>(tbox)[cell];
    const int g  = grid[cell];
    const int tc = tcls[cell];

    const int cj = cell % kS1;            // column -> xg
    const int ci = (cell / kS1) % kS0;    // row    -> yg
    const float tox = tb4.x, toy = tb4.y, tw = tb4.z, th = tb4.w;

    const float conf0 = sigm(f[0]);
    const float conf1 = sigm(f[1]);
    float pbx[2], pby[2], pbw[2], pbh[2];
    #pragma unroll
    for (int k = 0; k < 2; ++k) {
        pbx[k] = sigm(f[2 + 4 * k + 0]);
        pby[k] = sigm(f[2 + 4 * k + 1]);
        pbw[k] = sigm(f[2 + 4 * k + 2]);
        pbh[k] = sigm(f[2 + 4 * k + 3]);
    }

    // --- softmax over 20 classes; only the value at tc is needed ---
    float cmax = f[10];
    #pragma unroll
    for (int q = 11; q < 30; ++q) cmax = fmaxf(cmax, f[q]);
    float csum = 0.0f, et = 0.0f;
    #pragma unroll
    for (int q = 0; q < 20; ++q) {
        const float e = __expf(f[10 + q] - cmax);
        csum += e;
        et = (q == tc) ? e : et;     // constant q -> cndmask
    }
    const float cls_t = et / csum;

    // --- IOU of both predicted boxes vs target box ---
    const float x = (float)cj, y = (float)ci;
    const float tcx = (x + tox) * kInv7;
    const float tcy = (y + toy) * kInv7;
    const float thw = tw * 0.5f, thh = th * 0.5f;
    const float tarea = tw * th;

    float iou[2];
    #pragma unroll
    for (int k = 0; k < 2; ++k) {
        const float pcx = (x + pbx[k]) * kInv7;
        const float pcy = (y + pby[k]) * kInv7;
        const float pw = pbw[k], ph = pbh[k];
        const float tb_ = fminf(tcx + thw, pcx + pw * 0.5f) - fmaxf(tcx - thw, pcx - pw * 0.5f);
        const float lr_ = fminf(tcy + thh, pcy + ph * 0.5f) - fmaxf(tcy - thh, pcy - ph * 0.5f);
        float inter = tb_ * lr_;
        inter = (tb_ < 0.0f || lr_ < 0.0f) ? 0.0f : inter;
        iou[k] = inter / (tarea + pw * ph - inter);
    }

    const bool b1 = (iou[1] > iou[0]);     // tie -> box 0 (first-max)
    const float bx = b1 ? pbx[1] : pbx[0];
    const float by = b1 ? pby[1] : pby[0];
    const float bw = b1 ? pbw[1] : pbw[0];
    const float bh = b1 ? pbh[1] : pbh[0];
    const float conf_b = b1 ? conf1 : conf0;
    const float iou_b  = b1 ? iou[1] : iou[0];

    const float dx = bx - tox;
    const float dy = by - toy;
    const float dw = sqrtf(bw) - sqrtf(tw);
    const float dh = sqrtf(bh) - sqrtf(th);
    const float coord = dx * dx + dy * dy + dw * dw + dh * dh;
    const float d1 = conf_b - iou_b;
    const float d2 = 1.0f - cls_t;
    const float obj   = kWC * coord + d1 * d1 + d2 * d2;
    const float noobj = kWN * (conf0 * conf0 + conf1 * conf1);

    float v = (g == 1) ? obj : noobj;

    // --- wave64 shuffle reduce; one atomic per wave into a spread slot ---
    #pragma unroll
    for (int off = 32; off > 0; off >>= 1) v += __shfl_down(v, off, 64);
    if ((tid & 63) == 0) {
        atomicAdd(&partials[(blockIdx.x * 4 + wave) & (NSLOT - 1)], v);
    }
}

__global__ void finish_kernel(const float* __restrict__ partials,
                              float* __restrict__ out)
{
    float v = partials[threadIdx.x];      // 64 threads = 1 wave
    #pragma unroll
    for (int off = 32; off > 0; off >>= 1) v += __shfl_down(v, off, 64);
    if (threadIdx.x == 0) out[0] = v * (1.0f / kB);
}

} // namespace

extern "C" void kernel_launch(void* const* d_in, const int* in_sizes, int n_in,
                              void* d_out, int out_size, void* d_ws, size_t ws_size,
                              hipStream_t stream) {
    const float* pred = (const float*)d_in[0];
    const int*   grid = (const int*)d_in[1];
    const float* tbox = (const float*)d_in[2];
    const int*   tcls = (const int*)d_in[3];
    float* out      = (float*)d_out;
    float* partials = (float*)d_ws;       // 64 f32, poisoned -> zero each call

    hipMemsetAsync(partials, 0, NSLOT * sizeof(float), stream);
    yolo_loss_kernel<<<NBLK, TPB, 0, stream>>>(pred, grid, tbox, tcls, partials);
    finish_kernel<<<1, 64, 0, stream>>>(partials, out);
}

// Round 7
// 160.377 us; speedup vs baseline: 1.2727x; 1.2727x over previous
//
#include <hip/hip_runtime.h>
#include <math.h>

namespace {

constexpr int kB    = 16384;
constexpr int kS0   = 7;
constexpr int kS1   = 7;
constexpr int kD    = 30;
constexpr int kCells = kB * kS0 * kS1;   // 802816
constexpr int TPB   = 256;
constexpr int NBLK  = kCells / TPB;      // 3136 (exact)
constexpr int NSLOT = 64;                // spread-atomic partial slots
constexpr float kInv7 = 1.0f / 7.0f;
constexpr float kWC = 5.0f;
constexpr float kWN = 0.5f;

__device__ __forceinline__ float sigm(float x) {
    return 1.0f / (1.0f + __expf(-x));
}

// __launch_bounds__(256, 4): min 4 waves/EU -> VGPR cap 128. This STOPS the
// scheduler's max-occupancy register-minimization (r1/r5/r6 got VGPR=28-44,
// serializing the load batch to MLP~1). LDS caps us at 5 blocks/CU anyway,
// so nothing is lost by not targeting 8 waves/EU.
__global__ void __launch_bounds__(TPB, 4) yolo_loss_kernel(
    const float* __restrict__ pred,
    const int*   __restrict__ grid,
    const float* __restrict__ tbox,
    const int*   __restrict__ tcls,
    float* __restrict__ partials)   // 64 f32 slots in d_ws, pre-zeroed
{
    __shared__ float sp[TPB * kD];        // 30720 B staging for pred tile
    __shared__ float wsum[TPB / 64];

    const int tid   = threadIdx.x;
    const int cell0 = blockIdx.x * TPB;
    const int cell  = cell0 + tid;
    const int wave  = tid >> 6;
    const int lane  = tid & 63;

    // --- coalesced load batch: 1920 float4 = 256*7 + 128. Branchless ragged
    // tail: threads 128..255 redundantly load/store the SAME values as
    // threads 0..127 (benign race, identical data) so the whole
    // loads -> sched_barrier -> stores sequence is one straight-line
    // scheduling region with no basic-block boundaries.
    const float4* __restrict__ g4 =
        reinterpret_cast<const float4*>(pred + (size_t)cell0 * kD);
    float4* s4 = reinterpret_cast<float4*>(sp);
    const int etid = 1792 + (tid & 127);

    float4 r[8];
    #pragma unroll
    for (int k = 0; k < 7; ++k) r[k] = g4[tid + 256 * k];
    r[7] = g4[etid];

    const float4 tb4 = reinterpret_cast<const float4*>(tbox)[cell];
    const int g  = grid[cell];
    const int tc = tcls[cell];

    // Nothing may cross this point: all 11 global loads above must be issued
    // before the first ds_write below -> ~11 loads in flight (MLP ~11), one
    // progressive vmcnt drain instead of serial round trips.
    __builtin_amdgcn_sched_barrier(0);

    #pragma unroll
    for (int k = 0; k < 7; ++k) s4[tid + 256 * k] = r[k];
    s4[etid] = r[7];
    __syncthreads();

    const int cj = cell % kS1;            // column -> xg
    const int ci = (cell / kS1) % kS0;    // row    -> yg

    // --- per-cell 30 floats from LDS (float2, tid*30 even -> 8B aligned) ---
    float f[kD];
    {
        const float2* p2 = reinterpret_cast<const float2*>(sp + tid * kD);
        #pragma unroll
        for (int q = 0; q < kD / 2; ++q) {
            float2 t = p2[q];
            f[2 * q]     = t.x;
            f[2 * q + 1] = t.y;
        }
    }

    const float tox = tb4.x, toy = tb4.y, tw = tb4.z, th = tb4.w;

    const float conf0 = sigm(f[0]);
    const float conf1 = sigm(f[1]);
    float pbx[2], pby[2], pbw[2], pbh[2];
    #pragma unroll
    for (int k = 0; k < 2; ++k) {
        pbx[k] = sigm(f[2 + 4 * k + 0]);
        pby[k] = sigm(f[2 + 4 * k + 1]);
        pbw[k] = sigm(f[2 + 4 * k + 2]);
        pbh[k] = sigm(f[2 + 4 * k + 3]);
    }

    // --- softmax over 20 classes; only the value at tc is needed ---
    float cmax = f[10];
    #pragma unroll
    for (int q = 11; q < 30; ++q) cmax = fmaxf(cmax, f[q]);
    float csum = 0.0f, et = 0.0f;
    #pragma unroll
    for (int q = 0; q < 20; ++q) {
        const float e = __expf(f[10 + q] - cmax);
        csum += e;
        et = (q == tc) ? e : et;     // constant q -> cndmask
    }
    const float cls_t = et / csum;

    // --- IOU of both predicted boxes vs target box ---
    const float x = (float)cj, y = (float)ci;
    const float tcx = (x + tox) * kInv7;
    const float tcy = (y + toy) * kInv7;
    const float thw = tw * 0.5f, thh = th * 0.5f;
    const float tarea = tw * th;

    float iou[2];
    #pragma unroll
    for (int k = 0; k < 2; ++k) {
        const float pcx = (x + pbx[k]) * kInv7;
        const float pcy = (y + pby[k]) * kInv7;
        const float pw = pbw[k], ph = pbh[k];
        const float tb_ = fminf(tcx + thw, pcx + pw * 0.5f) - fmaxf(tcx - thw, pcx - pw * 0.5f);
        const float lr_ = fminf(tcy + thh, pcy + ph * 0.5f) - fmaxf(tcy - thh, pcy - ph * 0.5f);
        float inter = tb_ * lr_;
        inter = (tb_ < 0.0f || lr_ < 0.0f) ? 0.0f : inter;
        iou[k] = inter / (tarea + pw * ph - inter);
    }

    const bool b1 = (iou[1] > iou[0]);     // tie -> box 0 (first-max)
    const float bx = b1 ? pbx[1] : pbx[0];
    const float by = b1 ? pby[1] : pby[0];
    const float bw = b1 ? pbw[1] : pbw[0];
    const float bh = b1 ? pbh[1] : pbh[0];
    const float conf_b = b1 ? conf1 : conf0;
    const float iou_b  = b1 ? iou[1] : iou[0];

    const float dx = bx - tox;
    const float dy = by - toy;
    const float dw = sqrtf(bw) - sqrtf(tw);
    const float dh = sqrtf(bh) - sqrtf(th);
    const float coord = dx * dx + dy * dy + dw * dw + dh * dh;
    const float d1 = conf_b - iou_b;
    const float d2 = 1.0f - cls_t;
    const float obj   = kWC * coord + d1 * d1 + d2 * d2;
    const float noobj = kWN * (conf0 * conf0 + conf1 * conf1);

    float v = (g == 1) ? obj : noobj;

    // --- wave64 shuffle reduce, cross-wave via LDS, one spread atomic/block ---
    #pragma unroll
    for (int off = 32; off > 0; off >>= 1) v += __shfl_down(v, off, 64);
    if (lane == 0) wsum[wave] = v;
    __syncthreads();
    if (tid == 0) {
        // 3136 atomics over 64 slots = 49/slot: kills the single-address
        // atomic chain (~7ns each) seen in r1-r4.
        atomicAdd(&partials[blockIdx.x & (NSLOT - 1)],
                  wsum[0] + wsum[1] + wsum[2] + wsum[3]);
    }
}

__global__ void finish_kernel(const float* __restrict__ partials,
                              float* __restrict__ out)
{
    float v = partials[threadIdx.x];      // 64 threads = 1 wave
    #pragma unroll
    for (int off = 32; off > 0; off >>= 1) v += __shfl_down(v, off, 64);
    if (threadIdx.x == 0) out[0] = v * (1.0f / kB);
}

} // namespace

extern "C" void kernel_launch(void* const* d_in, const int* in_sizes, int n_in,
                              void* d_out, int out_size, void* d_ws, size_t ws_size,
                              hipStream_t stream) {
    const float* pred = (const float*)d_in[0];
    const int*   grid = (const int*)d_in[1];
    const float* tbox = (const float*)d_in[2];
    const int*   tcls = (const int*)d_in[3];
    float* out      = (float*)d_out;
    float* partials = (float*)d_ws;       // 64 f32, poisoned -> zero each call

    hipMemsetAsync(partials, 0, NSLOT * sizeof(float), stream);
    yolo_loss_kernel<<<NBLK, TPB, 0, stream>>>(pred, grid, tbox, tcls, partials);
    finish_kernel<<<1, 64, 0, stream>>>(partials, out);
}